// Round 13
// baseline (106.282 us; speedup 1.0000x reference)
//
#include <hip/hip_runtime.h>

typedef __attribute__((ext_vector_type(8))) short bf16x8;
typedef __attribute__((ext_vector_type(4))) float f32x4;
typedef __attribute__((ext_vector_type(2))) float f32x2;

// Native cast -> v_cvt_pk_bf16_f32 on gfx950 (RNE).
__device__ __forceinline__ unsigned short f2bf(float x) {
    union { __bf16 h; unsigned short s; } u;
    u.h = (__bf16)x;
    return u.s;
}

// SINGLE fused kernel, R13 = R12 with the grid barrier fixed.
// R12 lesson (measured): ACQUIRE-scope spin polls emit a cache invalidate per
// iteration on gfx950 -> 512 spinners = L2 invalidation storm -> 103us with
// VALUBusy 1% even when data is fully cached. Fix: RELAXED polls (plain load,
// no inv) + one acquire fence after exit; release add on entry.
// Co-residency: __launch_bounds__(256,2) -> 2 blocks/CU x 256 CU = 512 = grid.
__global__ __launch_bounds__(256, 2) void fused_all(
    const float* __restrict__ hs, const float* __restrict__ seqW,
    const float* __restrict__ hidW, const float* __restrict__ cpw,
    unsigned short* __restrict__ E16 /* [2][4096][32] bf16 */,
    unsigned* __restrict__ cnt, float* __restrict__ out)
{
    __shared__ float red[4][16][32];

    const int bid = blockIdx.x;
    const int tid = threadIdx.x;
    const int wv  = tid >> 6;
    const int l   = tid & 63;
    const int l15 = l & 15;
    const int g   = l >> 4;

    // ================= phase 1: embeddings gemm (R9 verbatim) =================
    {
        const bool hid = bid >= 256;
        const int mt  = hid ? bid - 256 : bid;
        const int m0  = mt * 16;
        const int mrow = m0 + l15;

        const float* __restrict__ W = hid ? hidW : seqW;
        size_t arow;
        if (hid) arow = ((size_t)(mrow >> 10) << 20) + (size_t)(mrow & 1023);
        else     arow = (size_t)mrow << 10;

        f32x4 acc0 = {0.f,0.f,0.f,0.f}, acc1 = {0.f,0.f,0.f,0.f};
        const int kbase = wv * 256;

        for (int ks = 0; ks < 8; ++ks) {
            const int kb = kbase + ks * 32 + g * 8;
            bf16x8 af, bf0, bf1;
            if (hid) {
                const float* pa = hs + arow + (size_t)kb * 1024;
                float a[8];
                #pragma unroll
                for (int j = 0; j < 8; ++j) a[j] = pa[(size_t)j * 1024];
                #pragma unroll
                for (int j = 0; j < 8; ++j) af[j] = (short)f2bf(a[j]);
            } else {
                const f32x4* pa = (const f32x4*)(hs + arow + kb);
                f32x4 a0 = pa[0], a1 = pa[1];
                af[0]=(short)f2bf(a0.x); af[1]=(short)f2bf(a0.y); af[2]=(short)f2bf(a0.z); af[3]=(short)f2bf(a0.w);
                af[4]=(short)f2bf(a1.x); af[5]=(short)f2bf(a1.y); af[6]=(short)f2bf(a1.z); af[7]=(short)f2bf(a1.w);
            }
            {
                const f32x4* pb = (const f32x4*)(W + (size_t)l15 * 1024 + kb);
                f32x4 b0 = pb[0], b1 = pb[1];
                bf0[0]=(short)f2bf(b0.x); bf0[1]=(short)f2bf(b0.y); bf0[2]=(short)f2bf(b0.z); bf0[3]=(short)f2bf(b0.w);
                bf0[4]=(short)f2bf(b1.x); bf0[5]=(short)f2bf(b1.y); bf0[6]=(short)f2bf(b1.z); bf0[7]=(short)f2bf(b1.w);
            }
            {
                const f32x4* pb = (const f32x4*)(W + (size_t)(l15 + 16) * 1024 + kb);
                f32x4 b0 = pb[0], b1 = pb[1];
                bf1[0]=(short)f2bf(b0.x); bf1[1]=(short)f2bf(b0.y); bf1[2]=(short)f2bf(b0.z); bf1[3]=(short)f2bf(b0.w);
                bf1[4]=(short)f2bf(b1.x); bf1[5]=(short)f2bf(b1.y); bf1[6]=(short)f2bf(b1.z); bf1[7]=(short)f2bf(b1.w);
            }
            acc0 = __builtin_amdgcn_mfma_f32_16x16x32_bf16(af, bf0, acc0, 0, 0, 0);
            acc1 = __builtin_amdgcn_mfma_f32_16x16x32_bf16(af, bf1, acc1, 0, 0, 0);
        }

        // C/D layout (m89-verified): col = lane&15, row = (lane>>4)*4 + reg
        #pragma unroll
        for (int r = 0; r < 4; ++r) {
            red[wv][4 * g + r][l15]      = acc0[r];
            red[wv][4 * g + r][l15 + 16] = acc1[r];
        }
        __syncthreads();

        const int o = tid * 2;
        const float* rf = &red[0][0][0];
        float vx = rf[o]     + rf[512 + o]     + rf[1024 + o]     + rf[1536 + o];
        float vy = rf[o + 1] + rf[512 + o + 1] + rf[1024 + o + 1] + rf[1536 + o + 1];
        if (!hid) {
            f32x2 w = *(const f32x2*)(cpw + (o & 31));
            vx *= w.x; vy *= w.y;
        }
        unsigned pk = (unsigned)f2bf(vx) | ((unsigned)f2bf(vy) << 16);
        unsigned short* Eo = E16 + (hid ? (size_t)4096 * 32 : 0) + (size_t)m0 * 32 + o;
        *(unsigned*)Eo = pk;
    }

    // ================= software grid barrier (relaxed spin) =================
    __threadfence();          // release: drain E16 stores to coherence point
    __syncthreads();
    if (tid == 0) {
        __hip_atomic_fetch_add(cnt, 1u, __ATOMIC_RELEASE, __HIP_MEMORY_SCOPE_AGENT);
        while (__hip_atomic_load(cnt, __ATOMIC_RELAXED, __HIP_MEMORY_SCOPE_AGENT) < 512u)
            __builtin_amdgcn_s_sleep(16);   // ~1k cycles between polls, no cache inv
    }
    __syncthreads();
    __threadfence();          // single acquire: invalidate stale E16 lines once

    // ================= phase 2: rank-32 MFMA k3 (R11), 2 tiles/block =========
    #pragma unroll
    for (int t = 0; t < 2; ++t) {
        const int tt = bid * 2 + t;            // 0..1023 tiles
        const int b  = tt >> 8;
        const int s0 = (((tt >> 4) & 15) * 64) + wv * 16;
        const int h0 = (tt & 15) * 64;

        const unsigned short* As = E16 + ((size_t)(b * 1024 + s0)) * 32;
        const unsigned short* Bh = E16 + (size_t)4096 * 32 + ((size_t)(b * 1024 + h0)) * 32;

        bf16x8 af = *(const bf16x8*)(As + (size_t)l15 * 32 + g * 8);
        bf16x8 bfr[4];
        #pragma unroll
        for (int j = 0; j < 4; ++j)
            bfr[j] = *(const bf16x8*)(Bh + (size_t)(4 * l15 + j) * 32 + g * 8);

        const f32x4 zero = {0.f, 0.f, 0.f, 0.f};
        f32x4 acc[4];
        #pragma unroll
        for (int j = 0; j < 4; ++j)
            acc[j] = __builtin_amdgcn_mfma_f32_16x16x32_bf16(af, bfr[j], zero, 0, 0, 0);

        #pragma unroll
        for (int r = 0; r < 4; ++r) {
            f32x4 v = { acc[0][r], acc[1][r], acc[2][r], acc[3][r] };
            float* orow = out + ((size_t)(b * 1024 + s0 + 4 * g + r)) * 1024 + h0 + 4 * l15;
            *(f32x4*)orow = v;
        }
    }
}

extern "C" void kernel_launch(void* const* d_in, const int* in_sizes, int n_in,
                              void* d_out, int out_size, void* d_ws, size_t ws_size,
                              hipStream_t stream) {
    const float* hs   = (const float*)d_in[0];
    // d_in[1] = all_indices: identically (n/H, n%H) -> computed implicitly
    const float* seqW = (const float*)d_in[2];
    const float* hidW = (const float*)d_in[3];
    const float* cpw  = (const float*)d_in[4];
    float* out = (float*)d_out;

    unsigned short* E16 = (unsigned short*)d_ws;                  // 512 KB bf16 E
    unsigned* cnt = (unsigned*)((char*)d_ws + (1 << 20));         // barrier counter

    hipMemsetAsync(cnt, 0, 4, stream);   // reset barrier (graph-capturable node)
    fused_all<<<512, 256, 0, stream>>>(hs, seqW, hidW, cpw, E16, cnt, out);
}

// Round 14
// 22.161 us; speedup vs baseline: 4.7959x; 4.7959x over previous
//
#include <hip/hip_runtime.h>

typedef __attribute__((ext_vector_type(8))) short bf16x8;
typedef __attribute__((ext_vector_type(4))) float f32x4;
typedef __attribute__((ext_vector_type(2))) float f32x2;

// Native cast -> v_cvt_pk_bf16_f32 on gfx950 (RNE).
__device__ __forceinline__ unsigned short f2bf(float x) {
    union { __bf16 h; unsigned short s; } u;
    u.h = (__bf16)x;
    return u.s;
}

// K1: fused skinny GEMMs (R9 structure), bf16 epilogue w/ cpw folded.
// R13 change: full unroll of the ks-loop so the scheduler can hoist the next
// iteration's 12 independent loads under the current cvt+MFMA chain (at 2
// blocks/CU there are only 2 waves/SIMD; cross-iteration ILP is the only
// latency hiding available). R10 measured warm gemm ~10us -> latency-bound,
// not HBM-bound.
__global__ __launch_bounds__(256) void gemm_fused(
    const float* __restrict__ hs, const float* __restrict__ seqW,
    const float* __restrict__ hidW, const float* __restrict__ cpw,
    unsigned short* __restrict__ E16 /* [2][4096][32] bf16 */)
{
    __shared__ float red[4][16][32];

    const int bid = blockIdx.x;
    const bool hid = bid >= 256;
    const int mt  = hid ? bid - 256 : bid;
    const int tid = threadIdx.x;
    const int wv  = tid >> 6;
    const int l   = tid & 63;
    const int l15 = l & 15;
    const int g   = l >> 4;
    const int m0  = mt * 16;
    const int mrow = m0 + l15;

    const float* __restrict__ W = hid ? hidW : seqW;
    size_t arow;
    if (hid) arow = ((size_t)(mrow >> 10) << 20) + (size_t)(mrow & 1023);
    else     arow = (size_t)mrow << 10;

    f32x4 acc0 = {0.f,0.f,0.f,0.f}, acc1 = {0.f,0.f,0.f,0.f};
    const int kbase = wv * 256;

    #pragma unroll
    for (int ks = 0; ks < 8; ++ks) {
        const int kb = kbase + ks * 32 + g * 8;
        bf16x8 af, bf0, bf1;
        if (hid) {
            const float* pa = hs + arow + (size_t)kb * 1024;
            float a[8];
            #pragma unroll
            for (int j = 0; j < 8; ++j) a[j] = pa[(size_t)j * 1024];
            #pragma unroll
            for (int j = 0; j < 8; ++j) af[j] = (short)f2bf(a[j]);
        } else {
            const f32x4* pa = (const f32x4*)(hs + arow + kb);
            f32x4 a0 = pa[0], a1 = pa[1];
            af[0]=(short)f2bf(a0.x); af[1]=(short)f2bf(a0.y); af[2]=(short)f2bf(a0.z); af[3]=(short)f2bf(a0.w);
            af[4]=(short)f2bf(a1.x); af[5]=(short)f2bf(a1.y); af[6]=(short)f2bf(a1.z); af[7]=(short)f2bf(a1.w);
        }
        {
            const f32x4* pb = (const f32x4*)(W + (size_t)l15 * 1024 + kb);
            f32x4 b0 = pb[0], b1 = pb[1];
            bf0[0]=(short)f2bf(b0.x); bf0[1]=(short)f2bf(b0.y); bf0[2]=(short)f2bf(b0.z); bf0[3]=(short)f2bf(b0.w);
            bf0[4]=(short)f2bf(b1.x); bf0[5]=(short)f2bf(b1.y); bf0[6]=(short)f2bf(b1.z); bf0[7]=(short)f2bf(b1.w);
        }
        {
            const f32x4* pb = (const f32x4*)(W + (size_t)(l15 + 16) * 1024 + kb);
            f32x4 b0 = pb[0], b1 = pb[1];
            bf1[0]=(short)f2bf(b0.x); bf1[1]=(short)f2bf(b0.y); bf1[2]=(short)f2bf(b0.z); bf1[3]=(short)f2bf(b0.w);
            bf1[4]=(short)f2bf(b1.x); bf1[5]=(short)f2bf(b1.y); bf1[6]=(short)f2bf(b1.z); bf1[7]=(short)f2bf(b1.w);
        }
        acc0 = __builtin_amdgcn_mfma_f32_16x16x32_bf16(af, bf0, acc0, 0, 0, 0);
        acc1 = __builtin_amdgcn_mfma_f32_16x16x32_bf16(af, bf1, acc1, 0, 0, 0);
    }

    // C/D layout (m89-verified): col = lane&15, row = (lane>>4)*4 + reg
    #pragma unroll
    for (int r = 0; r < 4; ++r) {
        red[wv][4 * g + r][l15]      = acc0[r];
        red[wv][4 * g + r][l15 + 16] = acc1[r];
    }
    __syncthreads();

    // Sum 4 wave-partials -> fold cpw (seq only) -> bf16 pack -> 4B store.
    const int o = tid * 2;
    const float* rf = &red[0][0][0];
    float vx = rf[o]     + rf[512 + o]     + rf[1024 + o]     + rf[1536 + o];
    float vy = rf[o + 1] + rf[512 + o + 1] + rf[1024 + o + 1] + rf[1536 + o + 1];
    if (!hid) {
        f32x2 w = *(const f32x2*)(cpw + (o & 31));
        vx *= w.x; vy *= w.y;
    }
    unsigned pk = (unsigned)f2bf(vx) | ((unsigned)f2bf(vy) << 16);
    unsigned short* Eo = E16 + (hid ? (size_t)4096 * 32 : 0) + (size_t)m0 * 32 + o;
    *(unsigned*)Eo = pk;
}

// K3: rank-32 GEMM via MFMA (R11 structure: coalesced f32x4 stores, 1024 blk).
// R13 change: NONTEMPORAL stores — out is write-once/never-re-read; bypassing
// L2 write-allocate should lift the 16.8MB fp32 stream from ~1.8 TB/s toward
// 4-5 TB/s (k3 measured ~9.5us vs ~3.5us write floor).
__global__ __launch_bounds__(256) void k3(const unsigned short* __restrict__ E16,
                                          float* __restrict__ out)
{
    const int tid = threadIdx.x;
    const int wv  = tid >> 6;
    const int l   = tid & 63;
    const int l15 = l & 15;
    const int g   = l >> 4;
    const int b   = blockIdx.z;
    const int s0  = blockIdx.y * 64 + wv * 16;
    const int h0  = blockIdx.x * 64;

    const unsigned short* As = E16 + ((size_t)(b * 1024 + s0)) * 32;
    const unsigned short* Bh = E16 + (size_t)4096 * 32 + ((size_t)(b * 1024 + h0)) * 32;

    bf16x8 af = *(const bf16x8*)(As + (size_t)l15 * 32 + g * 8);
    bf16x8 bfr[4];
    #pragma unroll
    for (int j = 0; j < 4; ++j)
        bfr[j] = *(const bf16x8*)(Bh + (size_t)(4 * l15 + j) * 32 + g * 8);

    const f32x4 zero = {0.f, 0.f, 0.f, 0.f};
    f32x4 acc[4];
    #pragma unroll
    for (int j = 0; j < 4; ++j)
        acc[j] = __builtin_amdgcn_mfma_f32_16x16x32_bf16(af, bfr[j], zero, 0, 0, 0);

    #pragma unroll
    for (int r = 0; r < 4; ++r) {
        f32x4 v = { acc[0][r], acc[1][r], acc[2][r], acc[3][r] };
        float* orow = out + ((size_t)(b * 1024 + s0 + 4 * g + r)) * 1024 + h0 + 4 * l15;
        __builtin_nontemporal_store(v, (f32x4*)orow);
    }
}

extern "C" void kernel_launch(void* const* d_in, const int* in_sizes, int n_in,
                              void* d_out, int out_size, void* d_ws, size_t ws_size,
                              hipStream_t stream) {
    const float* hs   = (const float*)d_in[0];
    // d_in[1] = all_indices: identically (n/H, n%H) -> computed implicitly
    const float* seqW = (const float*)d_in[2];
    const float* hidW = (const float*)d_in[3];
    const float* cpw  = (const float*)d_in[4];
    float* out = (float*)d_out;

    unsigned short* E16 = (unsigned short*)d_ws;   // [2][4096][32] bf16, 512 KB

    gemm_fused<<<512, 256, 0, stream>>>(hs, seqW, hidW, cpw, E16);
    dim3 grid3(16, 16, 4);
    k3<<<grid3, 256, 0, stream>>>(E16, out);
}